// Round 1
// baseline (103.762 us; speedup 1.0000x reference)
//
#include <hip/hip_runtime.h>
#include <hip/hip_bf16.h>

// CapsuleLinear, B=32, I=512, L=64, O=128, J=64, 3 routing iterations.
// Algebraic fusion: never materialize priors (512 MiB). Routing state kept in
// L-space:  out = W_o @ xc,  wn = (G_o @ xc)/||out||,  G_o = W_o^T W_o.
// Kernel 1: G (128 x 64 x 64 fp32 = 2 MB) into d_ws.
// Kernel 2: one block per (b, group of 8 o's); x[b] in swizzled LDS; G column
// per thread in 64 VGPRs; 3 fused iterations; epilogue out = W @ xc.

#define CB 32
#define CI 512
#define CL 64
#define CO 128
#define CJ 64
#define OPB 8
#define NT 512
#define NITER 3

__global__ __launch_bounds__(256) void caps_gram(const float* __restrict__ wg,
                                                 float* __restrict__ Gw) {
  const int o = blockIdx.x;
  const int t = threadIdx.x;
  __shared__ float wl[64 * 65];  // padded: bank = (j + l) % 32
#pragma unroll
  for (int k = 0; k < 16; ++k) {
    int f = t + 256 * k;
    int j = f >> 6, l = f & 63;
    wl[j * 65 + l] = wg[(o << 12) + f];
  }
  __syncthreads();
  const int l1 = t >> 2;
  const int l2b = (t & 3) << 4;
  float acc[16];
#pragma unroll
  for (int m = 0; m < 16; ++m) acc[m] = 0.f;
#pragma unroll 4
  for (int j = 0; j < 64; ++j) {
    float wa = wl[j * 65 + l1];
#pragma unroll
    for (int m = 0; m < 16; ++m) acc[m] += wa * wl[j * 65 + l2b + m];
  }
#pragma unroll
  for (int m = 0; m < 16; ++m) Gw[(o << 12) + (l1 << 6) + l2b + m] = acc[m];
}

// x LDS layout: row i (64 floats) stored as 16 float4 units; unit u stored at
// slot u ^ (i & 7).  Row reads (per-thread float4) and column reads (per-lane
// scalar) are both bank-conflict-free.
__global__ __launch_bounds__(NT, 2) void caps_main(const float* __restrict__ xg,
                                                   const float* __restrict__ wg,
                                                   const float* __restrict__ Gw,
                                                   float* __restrict__ outg) {
  const int b = blockIdx.y;
  const int obase = blockIdx.x * OPB;
  const int t = threadIdx.x;
  const int w = t >> 6;     // wave id == local capsule index
  const int lane = t & 63;

  __shared__ __align__(16) float xs[CI * CL];           // 131072 B (swizzled)
  __shared__ __align__(16) float coefs[CI * OPB];       // 16384 B  exp(logits)
  __shared__ __align__(16) __hip_bfloat16 pbuf[8 * OPB * 64];  // 8192 B partials
  __shared__ __align__(16) float xc_s[OPB * 64];        // 2048 B
  __shared__ __align__(16) float wn_s[OPB * 64];        // 2048 B
  __shared__ float red_s[OPB * 8];                      // 256 B softmax sums

  // G column into registers: g_reg[l2] = G[obase+w][l2][lane]  (G symmetric)
  float g_reg[64];
  {
    const float* Gp = Gw + ((obase + w) << 12) + lane;
#pragma unroll
    for (int l2 = 0; l2 < 64; ++l2) g_reg[l2] = Gp[l2 << 6];
  }

  // stage x[b] -> LDS, swizzled; global reads fully coalesced float4
  {
    const float4* xg4 = reinterpret_cast<const float4*>(xg + b * (CI * CL));
#pragma unroll
    for (int k = 0; k < 16; ++k) {
      int f4 = t + NT * k;       // 0..8191
      int i = f4 >> 4;
      int u = f4 & 15;
      float4 v = xg4[f4];
      *reinterpret_cast<float4*>(&xs[(i << 6) + ((u ^ (i & 7)) << 2)]) = v;
    }
  }
  __syncthreads();

  // xbar partials: wave w sums i in [64w, 64w+64) for column `lane`
  {
    float a0 = 0.f, a1 = 0.f;
#pragma unroll 8
    for (int ii = 0; ii < 64; ii += 2) {
      int i0 = (w << 6) + ii;
      int i1 = i0 + 1;
      a0 += xs[(i0 << 6) + ((((lane >> 2) ^ (i0 & 7)) << 2) | (lane & 3))];
      a1 += xs[(i1 << 6) + ((((lane >> 2) ^ (i1 & 7)) << 2) | (lane & 3))];
    }
    pbuf[(w << 9) + lane] = __float2bfloat16(a0 + a1);
  }
  __syncthreads();
  {
    float s = 0.f;
#pragma unroll
    for (int g = 0; g < 8; ++g) s += __bfloat162float(pbuf[(g << 9) + lane]);
    xc_s[(w << 6) + lane] = s * (1.0f / 512.0f);   // xc_0 = xbar for all 8 o's
  }
  __syncthreads();

  for (int it = 0; it < NITER; ++it) {
    // --- u = G @ xc ; ||out||^2 = xc.u ; wn = u / max(||out||, eps) ---
    {
      const float* xcp = &xc_s[w << 6];
      float u0 = 0.f, u1 = 0.f, u2 = 0.f, u3 = 0.f;
#pragma unroll
      for (int l2 = 0; l2 < 64; l2 += 4) {
        u0 += g_reg[l2 + 0] * xcp[l2 + 0];
        u1 += g_reg[l2 + 1] * xcp[l2 + 1];
        u2 += g_reg[l2 + 2] * xcp[l2 + 2];
        u3 += g_reg[l2 + 3] * xcp[l2 + 3];
      }
      float u = (u0 + u1) + (u2 + u3);
      float s = u * xcp[lane];
#pragma unroll
      for (int m = 32; m; m >>= 1) s += __shfl_xor(s, m, 64);
      float norm = sqrtf(fmaxf(s, 0.f));
      wn_s[(w << 6) + lane] = u / fmaxf(norm, 1e-12f);
    }
    __syncthreads();

    // --- logits row i = t for 8 capsules; exp; stash; per-o wave sums ---
    // |logits| <= ||x_i|| * sigma_max(W_o) ~ 2.5, so softmax without max-sub
    // is numerically safe (identical to reference up to fp rounding).
    {
      const int i = t;
      const int sw = i & 7;
      float acc[OPB];
#pragma unroll
      for (int o = 0; o < OPB; ++o) acc[o] = 0.f;
#pragma unroll
      for (int k = 0; k < 16; ++k) {
        float4 xv = *reinterpret_cast<const float4*>(&xs[(i << 6) + ((k ^ sw) << 2)]);
#pragma unroll
        for (int o = 0; o < OPB; ++o) {
          float4 wv = *reinterpret_cast<const float4*>(&wn_s[(o << 6) + (k << 2)]);
          acc[o] += xv.x * wv.x + xv.y * wv.y + xv.z * wv.z + xv.w * wv.w;
        }
      }
      float e[OPB];
#pragma unroll
      for (int o = 0; o < OPB; ++o) e[o] = __expf(acc[o]);
      // 16B-slot XOR on (i&1) spreads the two float4 writes across banks
      const int s0 = (i & 1) << 2;
      *reinterpret_cast<float4*>(&coefs[(i << 3) + s0]) =
          make_float4(e[0], e[1], e[2], e[3]);
      *reinterpret_cast<float4*>(&coefs[(i << 3) + (s0 ^ 4)]) =
          make_float4(e[4], e[5], e[6], e[7]);
#pragma unroll
      for (int o = 0; o < OPB; ++o) {
        float s = e[o];
#pragma unroll
        for (int m = 32; m; m >>= 1) s += __shfl_xor(s, m, 64);
        if (lane == 0) red_s[(o << 3) + w] = s;
      }
    }
    __syncthreads();

    // --- xc partials: wave w covers i in [64w, 64w+64), lane = l ---
    {
      float acc[OPB];
#pragma unroll
      for (int o = 0; o < OPB; ++o) acc[o] = 0.f;
#pragma unroll 8
      for (int ii = 0; ii < 64; ++ii) {
        const int i = (w << 6) + ii;
        const float xv =
            xs[(i << 6) + ((((lane >> 2) ^ (i & 7)) << 2) | (lane & 3))];
        const int s0 = (i & 1) << 2;
        const float4 c0 = *reinterpret_cast<const float4*>(&coefs[(i << 3) + s0]);
        const float4 c1 = *reinterpret_cast<const float4*>(&coefs[(i << 3) + (s0 ^ 4)]);
        acc[0] += c0.x * xv; acc[1] += c0.y * xv;
        acc[2] += c0.z * xv; acc[3] += c0.w * xv;
        acc[4] += c1.x * xv; acc[5] += c1.y * xv;
        acc[6] += c1.z * xv; acc[7] += c1.w * xv;
      }
#pragma unroll
      for (int o = 0; o < OPB; ++o)
        pbuf[(w << 9) + (o << 6) + lane] = __float2bfloat16(acc[o]);
    }
    __syncthreads();

    // --- finalize xc for capsule o = w ---
    {
      float se = 0.f;
#pragma unroll
      for (int g = 0; g < 8; ++g) se += red_s[(w << 3) + g];
      float s = 0.f;
#pragma unroll
      for (int g = 0; g < 8; ++g)
        s += __bfloat162float(pbuf[(g << 9) + (w << 6) + lane]);
      xc_s[(w << 6) + lane] = s / se;
    }
    __syncthreads();
  }

  // --- epilogue: out[b, obase+w, j=lane] = sum_l W[o][j][l] * xc[o][l] ---
  {
    const float* Wp = wg + ((((obase + w) << 6) + lane) << 6);
    float a0 = 0.f, a1 = 0.f, a2 = 0.f, a3 = 0.f;
#pragma unroll
    for (int k = 0; k < 16; ++k) {
      float4 wv = *reinterpret_cast<const float4*>(&Wp[k << 2]);
      float4 xv = *reinterpret_cast<const float4*>(&xc_s[(w << 6) + (k << 2)]);
      a0 += wv.x * xv.x; a1 += wv.y * xv.y;
      a2 += wv.z * xv.z; a3 += wv.w * xv.w;
    }
    outg[((b << 7) + obase + w) * 64 + lane] = (a0 + a1) + (a2 + a3);
  }
}

extern "C" void kernel_launch(void* const* d_in, const int* in_sizes, int n_in,
                              void* d_out, int out_size, void* d_ws, size_t ws_size,
                              hipStream_t stream) {
  const float* x = (const float*)d_in[0];     // (32, 512, 64) fp32
  const float* wgt = (const float*)d_in[1];   // (128, 64, 64) fp32
  float* out = (float*)d_out;                 // (32, 128, 64) fp32
  float* G = (float*)d_ws;                    // 128*64*64 fp32 = 2 MB

  caps_gram<<<dim3(CO), dim3(256), 0, stream>>>(wgt, G);
  caps_main<<<dim3(CO / OPB, CB), dim3(NT), 0, stream>>>(x, wgt, G, out);
}

// Round 2
// 77.500 us; speedup vs baseline: 1.3389x; 1.3389x over previous
//
#include <hip/hip_runtime.h>
#include <hip/hip_fp16.h>

// CapsuleLinear, B=32, I=512, L=64, O=128, J=64, 3 routing iterations.
// Algebraic fusion (no priors):  out = W_o @ xc,  wn = (G_o @ xc)/||out||,
// G_o = W_o^T W_o (precomputed, 2 MB in d_ws).
// Main kernel: block = (b, 8 capsules), 512 blocks, 2 blocks/CU (77.8 KB LDS).
// x[b] staged fp16 in LDS with 16B-unit XOR swizzle; per-wave-per-capsule xc
// pass with fused wn; 2 syncthreads per iteration.

#define CB 32
#define CI 512
#define CL 64
#define CO 128
#define OPB 8
#define NT 512
#define NITER 3

__global__ __launch_bounds__(256) void caps_gram(const float* __restrict__ wg,
                                                 float* __restrict__ Gw) {
  const int o = blockIdx.x;
  const int t = threadIdx.x;
  __shared__ float wl[64 * 65];  // padded: bank = (j + l) % 32
#pragma unroll
  for (int k = 0; k < 16; ++k) {
    int f = t + 256 * k;
    int j = f >> 6, l = f & 63;
    wl[j * 65 + l] = wg[(o << 12) + f];
  }
  __syncthreads();
  const int l1 = t >> 2;
  const int l2b = (t & 3) << 4;
  float acc[16];
#pragma unroll
  for (int m = 0; m < 16; ++m) acc[m] = 0.f;
#pragma unroll 4
  for (int j = 0; j < 64; ++j) {
    float wa = wl[j * 65 + l1];
#pragma unroll
    for (int m = 0; m < 16; ++m) acc[m] += wa * wl[j * 65 + l2b + m];
  }
#pragma unroll
  for (int m = 0; m < 16; ++m) Gw[(o << 12) + (l1 << 6) + l2b + m] = acc[m];
}

// wn = (G @ xc) / max(||out||, eps), where ||out||^2 = xc^T G xc.
// g kept by reference-to-array so it stays in registers when inlined.
__device__ __forceinline__ void wn_from_xc(const float (&g)[64],
                                           const float* __restrict__ xcp,
                                           int lane, float* __restrict__ wn_out) {
  float u0 = 0.f, u1 = 0.f, u2 = 0.f, u3 = 0.f;
#pragma unroll
  for (int l2 = 0; l2 < 64; l2 += 4) {
    u0 += g[l2 + 0] * xcp[l2 + 0];
    u1 += g[l2 + 1] * xcp[l2 + 1];
    u2 += g[l2 + 2] * xcp[l2 + 2];
    u3 += g[l2 + 3] * xcp[l2 + 3];
  }
  float uv = (u0 + u1) + (u2 + u3);
  float sq = uv * xcp[lane];
#pragma unroll
  for (int m = 32; m; m >>= 1) sq += __shfl_xor(sq, m, 64);
  float nrm = sqrtf(fmaxf(sq, 0.f));
  wn_out[lane] = uv / fmaxf(nrm, 1e-12f);
}

__global__ __launch_bounds__(NT, 4) void caps_main(const float* __restrict__ xg,
                                                   const float* __restrict__ wg,
                                                   const float* __restrict__ Gw,
                                                   float* __restrict__ outg) {
  const int b = blockIdx.y;
  const int obase = blockIdx.x * OPB;
  const int t = threadIdx.x;
  const int w = t >> 6;      // wave id == local capsule index
  const int lane = t & 63;
  const int r = lane >> 3;   // row offset within groups of 8
  const int u = lane & 7;    // 8-column unit index

  __shared__ __align__(16) __half xs[CI * CL];      // 65536 B, swizzled units
  __shared__ __align__(16) __half coefT[OPB * CI];  // 8192 B  exp(logits), [o][i]
  __shared__ __align__(16) float xc_s[OPB * 64];    // 2048 B
  __shared__ __align__(16) float wn_s[OPB * 64];    // 2048 B
  // total 77824 B -> 2 blocks/CU

  // G column into registers (G symmetric): g_reg[l2] = G[obase+w][l2][lane]
  float g_reg[64];
  {
    const float* Gp = Gw + ((obase + w) << 12) + lane;
#pragma unroll
    for (int l2 = 0; l2 < 64; ++l2) g_reg[l2] = Gp[l2 << 6];
  }

  // ---- stage x[b] -> fp16 LDS; row i = 8 units of 8 halves; unit uu at slot
  // uu^(i&7). Global reads coalesced (wave covers contiguous 2 KB per step).
  {
    const float4* xg4 = reinterpret_cast<const float4*>(xg + b * (CI * CL));
#pragma unroll
    for (int k = 0; k < 8; ++k) {
      int f = t + NT * k;       // unit id 0..4095
      int i = f >> 3, uu = f & 7;
      float4 a = xg4[2 * f];
      float4 c = xg4[2 * f + 1];
      __half2 h[4];
      h[0] = __floats2half2_rn(a.x, a.y);
      h[1] = __floats2half2_rn(a.z, a.w);
      h[2] = __floats2half2_rn(c.x, c.y);
      h[3] = __floats2half2_rn(c.z, c.w);
      *reinterpret_cast<uint4*>(&xs[(i << 6) + ((uu ^ (i & 7)) << 3)]) =
          *reinterpret_cast<const uint4*>(h);
    }
  }
  __syncthreads();

  // per-lane base into xs for the row-scan passes: row i = 8s + r, unit u;
  // i&7 == r, so slot = u^r is loop-invariant; step = 512 halves (1024 B).
  const __half* xbase = &xs[(r << 6) + ((u ^ r) << 3)];

  // ---- xbar (uniform-coef scan) + fused wn0; each wave does its own o=w ----
  {
    float a0 = 0.f, a1 = 0.f, a2 = 0.f, a3 = 0.f;
    float a4 = 0.f, a5 = 0.f, a6 = 0.f, a7 = 0.f;
#pragma unroll 4
    for (int s = 0; s < 64; ++s) {
      uint4 xv = *reinterpret_cast<const uint4*>(xbase + (s << 9));
      const __half2* hp = reinterpret_cast<const __half2*>(&xv);
      float2 f0 = __half22float2(hp[0]);
      float2 f1 = __half22float2(hp[1]);
      float2 f2 = __half22float2(hp[2]);
      float2 f3 = __half22float2(hp[3]);
      a0 += f0.x; a1 += f0.y; a2 += f1.x; a3 += f1.y;
      a4 += f2.x; a5 += f2.y; a6 += f3.x; a7 += f3.y;
    }
#pragma unroll
    for (int m = 8; m <= 32; m <<= 1) {
      a0 += __shfl_xor(a0, m, 64); a1 += __shfl_xor(a1, m, 64);
      a2 += __shfl_xor(a2, m, 64); a3 += __shfl_xor(a3, m, 64);
      a4 += __shfl_xor(a4, m, 64); a5 += __shfl_xor(a5, m, 64);
      a6 += __shfl_xor(a6, m, 64); a7 += __shfl_xor(a7, m, 64);
    }
    // select a[r] with static indices (avoid runtime-indexed register array)
    float t0 = (r & 1) ? a1 : a0, t1 = (r & 1) ? a3 : a2;
    float t2 = (r & 1) ? a5 : a4, t3 = (r & 1) ? a7 : a6;
    float s0 = (r & 2) ? t1 : t0, s1 = (r & 2) ? t3 : t2;
    float val = (r & 4) ? s1 : s0;
    xc_s[(w << 6) + (u << 3) + r] = val * (1.0f / 512.0f);
    wn_from_xc(g_reg, &xc_s[w << 6], lane, &wn_s[w << 6]);
  }
  __syncthreads();

  for (int it = 0; it < NITER; ++it) {
    // ---- A: logits row i = t for 8 capsules; exp -> coefT[o][i] ----
    // |logits| <= ||x_i||*sigma_max(W_o) ~ 2.5: softmax w/o max-sub is safe,
    // and exp(logits) in [0.07, 13.5] fits fp16.
    {
      const int i = t;
      const int sw = i & 7;
      const __half* xrow = &xs[i << 6];
      float acc[8];
#pragma unroll
      for (int o = 0; o < 8; ++o) acc[o] = 0.f;
#pragma unroll
      for (int k = 0; k < 8; ++k) {
        uint4 xv = *reinterpret_cast<const uint4*>(xrow + ((k ^ sw) << 3));
        const __half2* hp = reinterpret_cast<const __half2*>(&xv);
        float2 f0 = __half22float2(hp[0]);
        float2 f1 = __half22float2(hp[1]);
        float2 f2 = __half22float2(hp[2]);
        float2 f3 = __half22float2(hp[3]);
#pragma unroll
        for (int o = 0; o < 8; ++o) {
          const float* wp = &wn_s[(o << 6) + (k << 3)];
          float4 w0 = *reinterpret_cast<const float4*>(wp);
          float4 w1 = *reinterpret_cast<const float4*>(wp + 4);
          acc[o] += f0.x * w0.x + f0.y * w0.y + f1.x * w0.z + f1.y * w0.w +
                    f2.x * w1.x + f2.y * w1.y + f3.x * w1.z + f3.y * w1.w;
        }
      }
#pragma unroll
      for (int o = 0; o < 8; ++o)
        coefT[(o << 9) + i] = __float2half(__expf(acc[o]));
    }
    __syncthreads();

    // ---- B: xc for o=w (whole wave scans all 512 rows) + fused wn ----
    {
      const __half* cw = &coefT[w << 9];
      float a0 = 0.f, a1 = 0.f, a2 = 0.f, a3 = 0.f;
      float a4 = 0.f, a5 = 0.f, a6 = 0.f, a7 = 0.f;
      float se = 0.f;
#pragma unroll 4
      for (int s = 0; s < 64; ++s) {
        uint4 xv = *reinterpret_cast<const uint4*>(xbase + (s << 9));
        float c = __half2float(cw[(s << 3) + r]);
        se += c;
        const __half2* hp = reinterpret_cast<const __half2*>(&xv);
        float2 f0 = __half22float2(hp[0]);
        float2 f1 = __half22float2(hp[1]);
        float2 f2 = __half22float2(hp[2]);
        float2 f3 = __half22float2(hp[3]);
        a0 += c * f0.x; a1 += c * f0.y; a2 += c * f1.x; a3 += c * f1.y;
        a4 += c * f2.x; a5 += c * f2.y; a6 += c * f3.x; a7 += c * f3.y;
      }
#pragma unroll
      for (int m = 8; m <= 32; m <<= 1) {
        a0 += __shfl_xor(a0, m, 64); a1 += __shfl_xor(a1, m, 64);
        a2 += __shfl_xor(a2, m, 64); a3 += __shfl_xor(a3, m, 64);
        a4 += __shfl_xor(a4, m, 64); a5 += __shfl_xor(a5, m, 64);
        a6 += __shfl_xor(a6, m, 64); a7 += __shfl_xor(a7, m, 64);
        se += __shfl_xor(se, m, 64);
      }
      float inv = 1.0f / se;
      float t0 = (r & 1) ? a1 : a0, t1 = (r & 1) ? a3 : a2;
      float t2 = (r & 1) ? a5 : a4, t3 = (r & 1) ? a7 : a6;
      float s0 = (r & 2) ? t1 : t0, s1 = (r & 2) ? t3 : t2;
      float val = (r & 4) ? s1 : s0;
      xc_s[(w << 6) + (u << 3) + r] = val * inv;
      if (it < NITER - 1)
        wn_from_xc(g_reg, &xc_s[w << 6], lane, &wn_s[w << 6]);
    }
    __syncthreads();
  }

  // ---- epilogue: out[b, obase+w, j=lane] = sum_l W[o][j][l] * xc[o][l] ----
  {
    const float* Wp = wg + ((((obase + w) << 6) + lane) << 6);
    float a0 = 0.f, a1 = 0.f, a2 = 0.f, a3 = 0.f;
#pragma unroll
    for (int k = 0; k < 16; ++k) {
      float4 wv = *reinterpret_cast<const float4*>(&Wp[k << 2]);
      float4 xv = *reinterpret_cast<const float4*>(&xc_s[(w << 6) + (k << 2)]);
      a0 += wv.x * xv.x; a1 += wv.y * xv.y;
      a2 += wv.z * xv.z; a3 += wv.w * xv.w;
    }
    outg[((b << 7) + obase + w) * 64 + lane] = (a0 + a1) + (a2 + a3);
  }
}

extern "C" void kernel_launch(void* const* d_in, const int* in_sizes, int n_in,
                              void* d_out, int out_size, void* d_ws, size_t ws_size,
                              hipStream_t stream) {
  const float* x = (const float*)d_in[0];     // (32, 512, 64) fp32
  const float* wgt = (const float*)d_in[1];   // (128, 64, 64) fp32
  float* out = (float*)d_out;                 // (32, 128, 64) fp32
  float* G = (float*)d_ws;                    // 128*64*64 fp32 = 2 MB

  caps_gram<<<dim3(CO), dim3(256), 0, stream>>>(wgt, G);
  caps_main<<<dim3(CO / OPB, CB), dim3(NT), 0, stream>>>(x, wgt, G, out);
}

// Round 4
// 40.967 us; speedup vs baseline: 2.5328x; 1.8918x over previous
//
#include <hip/hip_runtime.h>
#include <hip/hip_fp16.h>

// CapsuleLinear, B=32, I=512, L=64, O=128, J=64, 3 routing iterations.
// Algebraic fusion (no priors):  out = W_o @ xc,  wn = (G_o @ xc)/||out||,
// G_o = W_o^T W_o (precomputed, 2 MB in d_ws).
// MFMA on v_mfma_f32_16x16x32_f16 for both matmul phases:
//  phase A: logits[i][o] = sum_l x[i][l] wn[o][l]   (A,B frags: b128 row reads)
//  phase B: xc[o][l]     = sum_i coef[o][i] x[i][l] (A: b128; B: scalar column
//           gather ds_read_u16 x8 — tr_b16 semantics were ambiguous, r3 FAIL)
// x fp16 in LDS as 16x16 subtiles (row-major in subtile, 32 B row pitch).
// 512 blocks = 2/CU (77 KB LDS), one full-chip round.

#define CB 32
#define CI 512
#define CL 64
#define CO 128
#define OPB 8
#define NT 512

typedef _Float16 half8 __attribute__((ext_vector_type(8)));
typedef float f32x4 __attribute__((ext_vector_type(4)));

__global__ __launch_bounds__(256) void caps_gram(const float* __restrict__ wg,
                                                 float* __restrict__ Gw) {
  const int o = blockIdx.x;
  const int t = threadIdx.x;
  __shared__ float wl[64 * 65];
#pragma unroll
  for (int k = 0; k < 16; ++k) {
    int f = t + 256 * k;
    int j = f >> 6, l = f & 63;
    wl[j * 65 + l] = wg[(o << 12) + f];
  }
  __syncthreads();
  const int l1 = t >> 2;
  const int l2b = (t & 3) << 4;
  float acc[16];
#pragma unroll
  for (int m = 0; m < 16; ++m) acc[m] = 0.f;
#pragma unroll 4
  for (int j = 0; j < 64; ++j) {
    float wa = wl[j * 65 + l1];
#pragma unroll
    for (int m = 0; m < 16; ++m) acc[m] += wa * wl[j * 65 + l2b + m];
  }
#pragma unroll
  for (int m = 0; m < 16; ++m) Gw[(o << 12) + (l1 << 6) + l2b + m] = acc[m];
}

__global__ __launch_bounds__(NT, 4) void caps_main(const float* __restrict__ xg,
                                                   const float* __restrict__ wg,
                                                   const float* __restrict__ Gw,
                                                   float* __restrict__ outg) {
  const int b = blockIdx.y;
  const int obase = blockIdx.x * OPB;
  const int t = threadIdx.x;
  const int w = t >> 6;          // wave id
  const int lane = t & 63;
  const int g = lane >> 4;       // 16-lane group
  const int o15 = lane & 15;     // MFMA row/col index
  const int oc = o15 & 7;

  // xs: 32 i-subtiles x 4 l-subtiles, each 16x16 halves row-major = 512 B.
  __shared__ __align__(16) _Float16 xs[CI * CL];        // 65536 B
  __shared__ __align__(16) _Float16 coefT[OPB * CI];    // 8192 B (unit-XOR swz)
  __shared__ __align__(16) _Float16 wn16[OPB * CL];     // 1024 B (unit-XOR swz)
  __shared__ __align__(16) float xc_s[OPB * CL];        // 2048 B
  __shared__ float se_part[OPB * OPB];                  // 256 B
  float* const xcpart = reinterpret_cast<float*>(coefT);  // [2][8][64] overlay
  char* const xs_b = reinterpret_cast<char*>(xs);
  char* const cf_b = reinterpret_cast<char*>(coefT);
  char* const wn_b = reinterpret_cast<char*>(wn16);
  // total 77056 B -> 2 blocks/CU

  // G column (fp32): g_reg[l2] = G[obase+w][l2][lane]  (G symmetric)
  float g_reg[64];
  {
    const float* Gp = Gw + ((obase + w) << 12) + lane;
#pragma unroll
    for (int l2 = 0; l2 < 64; ++l2) g_reg[l2] = Gp[l2 << 6];
  }

  // ---- stage x[b] -> fp16 subtiled LDS; coalesced float4 global reads ----
  {
    const float4* xg4 = reinterpret_cast<const float4*>(xg + b * (CI * CL));
#pragma unroll
    for (int k = 0; k < 8; ++k) {
      int f = t + NT * k;        // 8-half unit id: row i, l-unit lu
      int i = f >> 3, lu = f & 7;
      float4 a = xg4[2 * f];
      float4 c = xg4[2 * f + 1];
      union { _Float16 h[8]; uint4 u; } cv;
      cv.h[0] = (_Float16)a.x; cv.h[1] = (_Float16)a.y;
      cv.h[2] = (_Float16)a.z; cv.h[3] = (_Float16)a.w;
      cv.h[4] = (_Float16)c.x; cv.h[5] = (_Float16)c.y;
      cv.h[6] = (_Float16)c.z; cv.h[7] = (_Float16)c.w;
      int off = ((i >> 4) * 4 + (lu >> 1)) * 512 + (i & 15) * 32 + (lu & 1) * 16;
      *reinterpret_cast<uint4*>(xs_b + off) = cv.u;
    }
    // coef = 1.0 (fp16) for pass 0 (xbar); swizzle-invariant constant fill
    uint* cu = reinterpret_cast<uint*>(coefT);
#pragma unroll
    for (int k = 0; k < 4; ++k) cu[t + NT * k] = 0x3C003C00u;
    if (t < 64) se_part[t] = 64.f;  // per-wave coef sums for pass 0
  }
  __syncthreads();

  const int kh = w >> 2, nt = w & 3;  // phase-B: K-half, l-subtile
  // phase-B column-gather base (halfword pointer):
  // x[i = kh*256 + ks*32 + g*8 + j][nt*16 + o15], element j at +16 halves.
  const _Float16* xrd = reinterpret_cast<const _Float16*>(
      xs_b + ((kh * 16 + (g >> 1)) * 4 + nt) * 512 + ((lane & 16) << 4) +
      (o15 << 1));  // (g&1)*256 == (lane&16)<<4

  for (int pass = 0; pass < 4; ++pass) {
    if (pass > 0) {
      // ---- phase A: logits via MFMA; exp; coef+se ----
      half8 bw0 = *reinterpret_cast<const half8*>(wn_b + oc * 128 + ((g ^ oc) << 4));
      half8 bw1 = *reinterpret_cast<const half8*>(wn_b + oc * 128 + (((4 + g) ^ oc) << 4));
      float sacc = 0.f;
#pragma unroll
      for (int ti = 0; ti < 4; ++ti) {
        const int itb = (16 * w + 4 * ti) * 512;  // i-subtile (4w+ti) byte base
        half8 a0 = *reinterpret_cast<const half8*>(
            xs_b + itb + ((g >> 1) * 512) + o15 * 32 + ((g & 1) << 4));
        half8 a1 = *reinterpret_cast<const half8*>(
            xs_b + itb + ((2 + (g >> 1)) * 512) + o15 * 32 + ((g & 1) << 4));
        f32x4 d = {0.f, 0.f, 0.f, 0.f};
        d = __builtin_amdgcn_mfma_f32_16x16x32_f16(a0, bw0, d, 0, 0, 0);
        d = __builtin_amdgcn_mfma_f32_16x16x32_f16(a1, bw1, d, 0, 0, 0);
        // |logits| <= ||x_i||*sigma_max(W_o) ~ 2.5: no max-subtraction needed
        float e0 = __expf(d[0]), e1 = __expf(d[1]);
        float e2 = __expf(d[2]), e3 = __expf(d[3]);
        sacc += (e0 + e1) + (e2 + e3);
        if (o15 < 8) {  // valid capsule columns only
          int p = 8 * w + 2 * ti + (g >> 1);          // 8-half unit index (i>>3)
          int base = o15 * 1024 + ((p ^ o15) << 4) + ((g & 1) << 3);
          union { _Float16 h[2]; uint u; } p0, p1;
          p0.h[0] = (_Float16)e0; p0.h[1] = (_Float16)e1;
          p1.h[0] = (_Float16)e2; p1.h[1] = (_Float16)e3;
          *reinterpret_cast<uint*>(cf_b + base) = p0.u;
          *reinterpret_cast<uint*>(cf_b + base + 4) = p1.u;
        }
      }
      sacc += __shfl_xor(sacc, 16, 64);
      sacc += __shfl_xor(sacc, 32, 64);
      if (lane < 8) se_part[w * 8 + lane] = sacc;
      __syncthreads();
    }

    // ---- phase B: xc partials via MFMA (A=coef b128, B=x column gather) ----
    f32x4 d = {0.f, 0.f, 0.f, 0.f};
#pragma unroll
    for (int ks = 0; ks < 8; ++ks) {
      int p = kh * 32 + ks * 4 + g;
      half8 a = *reinterpret_cast<const half8*>(cf_b + oc * 1024 + ((p ^ oc) << 4));
      union { _Float16 h[8]; half8 v; } bf;
      const _Float16* xk = xrd + ks * 2048;  // +ks*4096 B
#pragma unroll
      for (int j = 0; j < 8; ++j) bf.h[j] = xk[j * 16];  // rows j, col fixed
      d = __builtin_amdgcn_mfma_f32_16x16x32_f16(a, bf.v, d, 0, 0, 0);
    }
    __syncthreads();  // all coefT reads done before overlay write
    if (lane < 32) {  // D rows 0-7 (valid o) live in lanes 0-31
#pragma unroll
      for (int r = 0; r < 4; ++r)
        xcpart[kh * 512 + (g * 4 + r) * 64 + nt * 16 + o15] = d[r];
    }
    __syncthreads();

    // ---- finalize: xc = (part0+part1)/se; wn = (G@xc)/||out|| ----
    {
      float se = 0.f;
#pragma unroll
      for (int g8 = 0; g8 < 8; ++g8) se += se_part[g8 * 8 + w];
      float xcv = (xcpart[w * 64 + lane] + xcpart[512 + w * 64 + lane]) / se;
      xc_s[(w << 6) + lane] = xcv;
      if (pass < 3) {
        const float* xcp = &xc_s[w << 6];
        float u0 = 0.f, u1 = 0.f, u2 = 0.f, u3 = 0.f;
#pragma unroll
        for (int l2 = 0; l2 < 64; l2 += 4) {
          u0 += g_reg[l2 + 0] * xcp[l2 + 0];
          u1 += g_reg[l2 + 1] * xcp[l2 + 1];
          u2 += g_reg[l2 + 2] * xcp[l2 + 2];
          u3 += g_reg[l2 + 3] * xcp[l2 + 3];
        }
        float uv = (u0 + u1) + (u2 + u3);
        float sq = uv * xcv;
#pragma unroll
        for (int m = 32; m; m >>= 1) sq += __shfl_xor(sq, m, 64);
        float wnv = uv / fmaxf(sqrtf(fmaxf(sq, 0.f)), 1e-12f);
        union { _Float16 hf; unsigned short us; } wc;
        wc.hf = (_Float16)wnv;
        *reinterpret_cast<unsigned short*>(
            wn_b + w * 128 + (((lane >> 3) ^ w) << 4) + ((lane & 7) << 1)) = wc.us;
      }
    }
    __syncthreads();
  }

  // ---- epilogue: out[b, obase+w, j=lane] = sum_l W[o][j][l] * xc[o][l] ----
  {
    const float* Wp = wg + ((((obase + w) << 6) + lane) << 6);
    float a0 = 0.f, a1 = 0.f, a2 = 0.f, a3 = 0.f;
#pragma unroll
    for (int k = 0; k < 16; ++k) {
      float4 wv = *reinterpret_cast<const float4*>(&Wp[k << 2]);
      float4 xv = *reinterpret_cast<const float4*>(&xc_s[(w << 6) + (k << 2)]);
      a0 += wv.x * xv.x; a1 += wv.y * xv.y;
      a2 += wv.z * xv.z; a3 += wv.w * xv.w;
    }
    outg[((b << 7) + obase + w) * 64 + lane] = (a0 + a1) + (a2 + a3);
  }
}

extern "C" void kernel_launch(void* const* d_in, const int* in_sizes, int n_in,
                              void* d_out, int out_size, void* d_ws, size_t ws_size,
                              hipStream_t stream) {
  const float* x = (const float*)d_in[0];     // (32, 512, 64) fp32
  const float* wgt = (const float*)d_in[1];   // (128, 64, 64) fp32
  float* out = (float*)d_out;                 // (32, 128, 64) fp32
  float* G = (float*)d_ws;                    // 128*64*64 fp32 = 2 MB

  caps_gram<<<dim3(CO), dim3(256), 0, stream>>>(wgt, G);
  caps_main<<<dim3(CO / OPB, CB), dim3(NT), 0, stream>>>(x, wgt, G, out);
}